// Round 13
// baseline (551.137 us; speedup 1.0000x reference)
//
#include <hip/hip_runtime.h>
#include <hip/hip_bf16.h>
#include <math.h>

// Problem constants
#define BB 8
#define SS 1024
#define DD 1024
#define HH 16
#define DHH 64
#define DFFN 4096
#define NROWS (BB*SS)   // 8192

typedef __attribute__((ext_vector_type(8))) short short8v;  // 8 bf16 (4 VGPRs)
typedef __attribute__((ext_vector_type(4))) float f32x4;
typedef __hip_bfloat16 bf16;

__device__ __forceinline__ float gelu_f(float x) {
    return 0.5f * x * (1.0f + erff(x * 0.70710678118654752440f));
}
__device__ __forceinline__ unsigned short bf16bits(float x) {
    bf16 h = __float2bfloat16(x);
    return *reinterpret_cast<unsigned short*>(&h);
}

#define AS1C const __attribute__((address_space(1))) void*
#define AS3P __attribute__((address_space(3))) void*
#define GLDS16(g, l) __builtin_amdgcn_global_load_lds((AS1C)(g), (AS3P)(l), 16, 0, 0)

// ---------------------------------------------------------------------------
// prep: w=softmax(elw), b5, catb in one launch
// ---------------------------------------------------------------------------
__global__ __launch_bounds__(256) void prep_k(const float* __restrict__ elw,
                                              const float* __restrict__ eb,
                                              const float* __restrict__ qb,
                                              const float* __restrict__ kb,
                                              const float* __restrict__ mb1,
                                              float* __restrict__ w_out,
                                              float* __restrict__ w_ws,
                                              float* __restrict__ b5,
                                              float* __restrict__ catb) {
    int t = threadIdx.x, blk = blockIdx.x;
    float e0 = elw[0], e1 = elw[1], e2 = elw[2], e3 = elw[3], e4 = elw[4];
    float mx = fmaxf(fmaxf(fmaxf(e0, e1), fmaxf(e2, e3)), e4);
    float x0 = expf(e0 - mx), x1 = expf(e1 - mx), x2 = expf(e2 - mx),
          x3 = expf(e3 - mx), x4 = expf(e4 - mx);
    float inv = 1.f / (x0 + x1 + x2 + x3 + x4);
    float w[5] = {x0 * inv, x1 * inv, x2 * inv, x3 * inv, x4 * inv};
    if (blk == 0 && t < 5) { w_out[t] = w[t]; w_ws[t] = w[t]; }
    if (blk < 4) {
        int i = blk * 256 + t;
        float acc = 0.f;
#pragma unroll
        for (int p = 0; p < 5; ++p) acc += w[p] * eb[p * DD + i];
        b5[i] = acc;
    } else {
        int i = (blk - 4) * 256 + t;
        if (i < 2560) {
            float v = (i < 1024) ? qb[i] : (i < 2048) ? kb[i - 1024] : mb1[i - 2048];
            catb[i] = v;
        }
    }
}

// ---------------------------------------------------------------------------
// combine_ewT: w5T[e][d] = bf16( sum_p w_p * ew[p][d][e] )
// ---------------------------------------------------------------------------
__global__ __launch_bounds__(256) void combine_ewT_k(const float* __restrict__ ew,
                                                     const float* __restrict__ w_ws,
                                                     bf16* __restrict__ w5T) {
    __shared__ float tile[32][33];
    float w0 = w_ws[0], w1 = w_ws[1], w2 = w_ws[2], w3 = w_ws[3], w4 = w_ws[4];
    int d0 = blockIdx.x * 32, e0 = blockIdx.y * 32;
    int tx = threadIdx.x & 31, ty = threadIdx.x >> 5;   // 32 x 8
#pragma unroll
    for (int i = 0; i < 32; i += 8) {
        size_t off = (size_t)(d0 + ty + i) * 1024 + e0 + tx;
        float acc = w0 * ew[off] + w1 * ew[1048576 + off] + w2 * ew[2097152 + off]
                  + w3 * ew[3145728 + off] + w4 * ew[4194304 + off];
        tile[ty + i][tx] = acc;
    }
    __syncthreads();
#pragma unroll
    for (int i = 0; i < 32; i += 8)
        w5T[(size_t)(e0 + ty + i) * 1024 + d0 + tx] = __float2bfloat16(tile[tx][ty + i]);
}

// ---------------------------------------------------------------------------
// tconv: in f32 [K,N] -> out bf16 [N,K]
// ---------------------------------------------------------------------------
__global__ __launch_bounds__(256) void tconv_k(const float* __restrict__ in,
                                               bf16* __restrict__ out,
                                               int K, int N) {
    __shared__ float tile[32][33];
    int k0 = blockIdx.x * 32, n0 = blockIdx.y * 32;
    int tx = threadIdx.x & 31, ty = threadIdx.x >> 5;   // 32 x 8
#pragma unroll
    for (int i = 0; i < 32; i += 8)
        tile[ty + i][tx] = in[(size_t)(k0 + ty + i) * N + n0 + tx];
    __syncthreads();
#pragma unroll
    for (int i = 0; i < 32; i += 8)
        out[(size_t)(n0 + ty + i) * K + k0 + tx] = __float2bfloat16(tile[tx][ty + i]);
}

// ---------------------------------------------------------------------------
// tconv5: five 1024x1024 f32->bf16 transposes in one launch
// ---------------------------------------------------------------------------
__global__ __launch_bounds__(256) void tconv5_k(
    const float* __restrict__ s0, const float* __restrict__ s1,
    const float* __restrict__ s2, const float* __restrict__ s3,
    const float* __restrict__ s4,
    bf16* __restrict__ d0, bf16* __restrict__ d1, bf16* __restrict__ d2,
    bf16* __restrict__ d3, bf16* __restrict__ d4) {
    const float* in; bf16* out;
    switch (blockIdx.z) {
        case 0: in = s0; out = d0; break;
        case 1: in = s1; out = d1; break;
        case 2: in = s2; out = d2; break;
        case 3: in = s3; out = d3; break;
        default: in = s4; out = d4; break;
    }
    __shared__ float tile[32][33];
    int k0 = blockIdx.x * 32, n0 = blockIdx.y * 32;
    int tx = threadIdx.x & 31, ty = threadIdx.x >> 5;   // 32 x 8
#pragma unroll
    for (int i = 0; i < 32; i += 8)
        tile[ty + i][tx] = in[(size_t)(k0 + ty + i) * 1024 + n0 + tx];
    __syncthreads();
#pragma unroll
    for (int i = 0; i < 32; i += 8)
        out[(size_t)(n0 + ty + i) * 1024 + k0 + tx] = __float2bfloat16(tile[tx][ty + i]);
}

// ---------------------------------------------------------------------------
// build_pe (bf16)
// ---------------------------------------------------------------------------
__global__ __launch_bounds__(256) void build_pe_k(const float* __restrict__ pos,
                                                  const float* __restrict__ tim,
                                                  bf16* __restrict__ pe) {
    int idx = blockIdx.x * 256 + threadIdx.x;   // over 1048576
    int s = idx >> 10, d = idx & 1023;
    float v = (d < 512) ? pos[s * 512 + d] : tim[s * 512 + (d - 512)];
    pe[idx] = __float2bfloat16(v);
}

// ---------------------------------------------------------------------------
// layernorm_pe: xacc = x + pp[s]; h = LN(xacc)*g+be  (fuses add_pe + LN1,
// saves one full 32MB read pass + a launch)
// ---------------------------------------------------------------------------
__global__ __launch_bounds__(256) void layernorm_pe_k(const float* __restrict__ x,
                                                      const float* __restrict__ pp,
                                                      const float* __restrict__ g,
                                                      const float* __restrict__ be,
                                                      float* __restrict__ xacc,
                                                      bf16* __restrict__ out) {
    int row = blockIdx.x;
    int srow = row & 1023;
    int t = threadIdx.x;
    float4 xv = *reinterpret_cast<const float4*>(&x[(size_t)row * DD + t * 4]);
    float4 pv = *reinterpret_cast<const float4*>(&pp[(size_t)srow * DD + t * 4]);
    xv.x += pv.x; xv.y += pv.y; xv.z += pv.z; xv.w += pv.w;
    *reinterpret_cast<float4*>(&xacc[(size_t)row * DD + t * 4]) = xv;
    float s  = xv.x + xv.y + xv.z + xv.w;
    float ss = xv.x * xv.x + xv.y * xv.y + xv.z * xv.z + xv.w * xv.w;
#pragma unroll
    for (int off = 32; off; off >>= 1) {
        s  += __shfl_down(s, off);
        ss += __shfl_down(ss, off);
    }
    __shared__ float sm[4], sv[4], stats[2];
    int w = t >> 6;
    if ((t & 63) == 0) { sm[w] = s; sv[w] = ss; }
    __syncthreads();
    if (t == 0) {
        float S1 = sm[0] + sm[1] + sm[2] + sm[3];
        float S2 = sv[0] + sv[1] + sv[2] + sv[3];
        float mean = S1 * (1.f / (float)DD);
        float var  = S2 * (1.f / (float)DD) - mean * mean;
        stats[0] = mean;
        stats[1] = rsqrtf(var + 1e-5f);
    }
    __syncthreads();
    float mean = stats[0], inv = stats[1];
    float4 gv = *reinterpret_cast<const float4*>(&g[t * 4]);
    float4 bv = *reinterpret_cast<const float4*>(&be[t * 4]);
    union { bf16 h[4]; uint2 u; } pk;
    pk.h[0] = __float2bfloat16((xv.x - mean) * inv * gv.x + bv.x);
    pk.h[1] = __float2bfloat16((xv.y - mean) * inv * gv.y + bv.y);
    pk.h[2] = __float2bfloat16((xv.z - mean) * inv * gv.z + bv.z);
    pk.h[3] = __float2bfloat16((xv.w - mean) * inv * gv.w + bv.w);
    *reinterpret_cast<uint2*>(&out[(size_t)row * DD + t * 4]) = pk.u;
}

// ---------------------------------------------------------------------------
// layernorm (bf16 out)
// ---------------------------------------------------------------------------
__global__ __launch_bounds__(256) void layernorm_k(const float* __restrict__ in,
                                                   const float* __restrict__ g,
                                                   const float* __restrict__ be,
                                                   bf16* __restrict__ out) {
    int row = blockIdx.x;
    int t = threadIdx.x;
    const float* x = in + (size_t)row * DD;
    float4 xv = *reinterpret_cast<const float4*>(&x[t * 4]);
    float s  = xv.x + xv.y + xv.z + xv.w;
    float ss = xv.x * xv.x + xv.y * xv.y + xv.z * xv.z + xv.w * xv.w;
#pragma unroll
    for (int off = 32; off; off >>= 1) {
        s  += __shfl_down(s, off);
        ss += __shfl_down(ss, off);
    }
    __shared__ float sm[4], sv[4], stats[2];
    int w = t >> 6;
    if ((t & 63) == 0) { sm[w] = s; sv[w] = ss; }
    __syncthreads();
    if (t == 0) {
        float S1 = sm[0] + sm[1] + sm[2] + sm[3];
        float S2 = sv[0] + sv[1] + sv[2] + sv[3];
        float mean = S1 * (1.f / (float)DD);
        float var  = S2 * (1.f / (float)DD) - mean * mean;
        stats[0] = mean;
        stats[1] = rsqrtf(var + 1e-5f);
    }
    __syncthreads();
    float mean = stats[0], inv = stats[1];
    float4 gv = *reinterpret_cast<const float4*>(&g[t * 4]);
    float4 bv = *reinterpret_cast<const float4*>(&be[t * 4]);
    union { bf16 h[4]; uint2 u; } pk;
    pk.h[0] = __float2bfloat16((xv.x - mean) * inv * gv.x + bv.x);
    pk.h[1] = __float2bfloat16((xv.y - mean) * inv * gv.y + bv.y);
    pk.h[2] = __float2bfloat16((xv.z - mean) * inv * gv.z + bv.z);
    pk.h[3] = __float2bfloat16((xv.w - mean) * inv * gv.w + bv.w);
    *reinterpret_cast<uint2*>(&out[(size_t)row * DD + t * 4]) = pk.u;
}

// ---------------------------------------------------------------------------
// Ring MFMA GEMM v4.2: 2-slot double buffer, 4 blocks/CU, pointer-increment
// staging, XOR swizzle, XCD-contiguous + group-M(8) ordering.
// LDK = A/BT row stride (for split-K); K = length processed this launch.
// SPLITK: grid doubled; upper half handles same tiles with caller-provided
// second K-segment pointers (A2/BT2) and writes to C1 instead of C0.
// OUTMODE: 0=f32 +bias(col)+res; 2=bf16 gelu(x+bias);
//          3=qkm split; 4=bf16 +bias(row); 6=bf16 raw partial (no bias/res)
// ---------------------------------------------------------------------------
template <int OUTMODE, bool SPLITK>
__global__ __launch_bounds__(256, 4) void gemm_ring(
    const bf16* __restrict__ A, const bf16* __restrict__ BT,
    const float* __restrict__ bias, const float* __restrict__ res,
    void* __restrict__ C0, void* __restrict__ C1, void* __restrict__ C2,
    int M, int N, int K, int LDK)
{
    constexpr int BM = 128, BN = 128;
    constexpr int SLOTB = (BM + BN) * 64;      // 16 KB per slot (A then B)
    __shared__ char lds[2 * SLOTB];            // 32 KB
    const int tid = threadIdx.x, lane = tid & 63, wid = tid >> 6;
    const int ql = lane & 15, g = lane >> 4;
    const int wr = wid >> 1, wc = wid & 1;

    int b0 = blockIdx.x, nwg = gridDim.x;
    int half = 0;
    if (SPLITK) {
        nwg >>= 1;
        if (b0 >= nwg) { half = 1; b0 -= nwg; A += K; BT += K; }
    }
    // XCD-contiguous chunks, then group-M(8) ordering for L2 reuse
    const int nby = N / BN;
    int id = (b0 & 7) * (nwg >> 3) + (b0 >> 3);
    const int gsz = 8 * nby;
    int grp = id / gsz, rem = id % gsz;
    const int bm = (grp * 8 + (rem & 7)) * BM;
    const int bn = (rem >> 3) * BN;

    const int id0 = tid, id1 = tid + 256;
    const int ra0 = id0 >> 2, ca0 = id0 & 3;
    const int ra1 = id1 >> 2, ca1 = id1 & 3;
    const bf16* ga0 = A  + (size_t)(bm + ra0) * LDK + ((ca0 ^ ((ra0 >> 1) & 3)) * 8);
    const bf16* ga1 = A  + (size_t)(bm + ra1) * LDK + ((ca1 ^ ((ra1 >> 1) & 3)) * 8);
    const bf16* gb0 = BT + (size_t)(bn + ra0) * LDK + ((ca0 ^ ((ra0 >> 1) & 3)) * 8);
    const bf16* gb1 = BT + (size_t)(bn + ra1) * LDK + ((ca1 ^ ((ra1 >> 1) & 3)) * 8);

    int aoff[4], boff[4];
#pragma unroll
    for (int i = 0; i < 4; ++i) {
        int row = wr * 64 + i * 16 + ql;
        aoff[i] = row * 64 + ((g ^ ((row >> 1) & 3)) * 16);
        int brow = wc * 64 + i * 16 + ql;
        boff[i] = BM * 64 + brow * 64 + ((g ^ ((brow >> 1) & 3)) * 16);
    }

    const int NT = K >> 5;
    auto STAGE = [&](int slot) {
        char* base = lds + slot * SLOTB;
        GLDS16(ga0, base + tid * 16);
        GLDS16(ga1, base + 4096 + tid * 16);
        GLDS16(gb0, base + 8192 + tid * 16);
        GLDS16(gb1, base + 12288 + tid * 16);
        ga0 += 32; ga1 += 32; gb0 += 32; gb1 += 32;
    };

    f32x4 acc[4][4] = {};
    STAGE(0);
    for (int t = 0; t < NT; ++t) {
        asm volatile("s_waitcnt vmcnt(0)" ::: "memory");
        __builtin_amdgcn_s_barrier();
        __builtin_amdgcn_sched_barrier(0);
        if (t + 1 < NT) STAGE((t + 1) & 1);
        __builtin_amdgcn_sched_barrier(0);
        char* slot = lds + (t & 1) * SLOTB;
        short8v af[4], bfr[4];
#pragma unroll
        for (int i = 0; i < 4; ++i) af[i]  = *(const short8v*)(slot + aoff[i]);
#pragma unroll
        for (int j = 0; j < 4; ++j) bfr[j] = *(const short8v*)(slot + boff[j]);
        __builtin_amdgcn_s_setprio(1);
#pragma unroll
        for (int i = 0; i < 4; ++i)
#pragma unroll
            for (int j = 0; j < 4; ++j)
                acc[i][j] = __builtin_amdgcn_mfma_f32_16x16x32_bf16(af[i], bfr[j], acc[i][j], 0, 0, 0);
        __builtin_amdgcn_s_setprio(0);
    }

    const int colbase = bn + wc * 64 + ql;
    const int rowbase = bm + wr * 64 + g * 4;
#pragma unroll
    for (int j = 0; j < 4; ++j) {
        int col = colbase + j * 16;
#pragma unroll
        for (int i = 0; i < 4; ++i) {
#pragma unroll
            for (int r = 0; r < 4; ++r) {
                int row = rowbase + i * 16 + r;
                float val = acc[i][j][r];
                if (OUTMODE == 0) {
                    val += bias[col];
                    if (res) val += res[(size_t)row * N + col];
                    ((float*)C0)[(size_t)row * N + col] = val;
                } else if (OUTMODE == 2) {
                    val = gelu_f(val + bias[col]);
                    ((bf16*)C0)[(size_t)row * N + col] = __float2bfloat16(val);
                } else if (OUTMODE == 3) {
                    val += bias[col];
                    if (col < 1024)
                        ((bf16*)C0)[(size_t)row * 1024 + col] = __float2bfloat16(val);
                    else if (col < 2048)
                        ((bf16*)C1)[(size_t)row * 1024 + (col - 1024)] = __float2bfloat16(val);
                    else
                        ((bf16*)C2)[(size_t)row * 512 + (col - 2048)] = __float2bfloat16(gelu_f(val));
                } else if (OUTMODE == 4) {
                    val += bias[row];
                    ((bf16*)C0)[(size_t)row * N + col] = __float2bfloat16(val);
                } else {   // 6: raw bf16 partial; half selects C0/C1
                    bf16* dst = half ? (bf16*)C1 : (bf16*)C0;
                    dst[(size_t)row * N + col] = __float2bfloat16(val);
                }
            }
        }
    }
}

// ---------------------------------------------------------------------------
// combine_ffn2: out = xacc + fb2[col] + P1 + P2   (f32 out, bf16 partials)
// ---------------------------------------------------------------------------
__global__ __launch_bounds__(256) void combine_ffn2_k(const float* __restrict__ xacc,
                                                      const float* __restrict__ fb2,
                                                      const bf16* __restrict__ P1,
                                                      const bf16* __restrict__ P2,
                                                      float* __restrict__ out) {
    int idx = blockIdx.x * 256 + threadIdx.x;    // over 2097152 (x4 elems)
    size_t e = (size_t)idx * 4;
    int col = (int)(e & 1023);
    float4 xv = *reinterpret_cast<const float4*>(&xacc[e]);
    float4 bv = *reinterpret_cast<const float4*>(&fb2[col]);
    ushort4 p1 = *reinterpret_cast<const ushort4*>(&P1[e]);
    ushort4 p2 = *reinterpret_cast<const ushort4*>(&P2[e]);
    union { unsigned u; float f; } c;
    float4 o;
    c.u = (unsigned)p1.x << 16; o.x = xv.x + bv.x + c.f;
    c.u = (unsigned)p2.x << 16; o.x += c.f;
    c.u = (unsigned)p1.y << 16; o.y = xv.y + bv.y + c.f;
    c.u = (unsigned)p2.y << 16; o.y += c.f;
    c.u = (unsigned)p1.z << 16; o.z = xv.z + bv.z + c.f;
    c.u = (unsigned)p2.z << 16; o.z += c.f;
    c.u = (unsigned)p1.w << 16; o.w = xv.w + bv.w + c.f;
    c.u = (unsigned)p2.w << 16; o.w += c.f;
    *reinterpret_cast<float4*>(&out[e]) = o;
}

// ---------------------------------------------------------------------------
// mech head
// ---------------------------------------------------------------------------
__global__ __launch_bounds__(256) void mech_head_k(const bf16* __restrict__ tin,
                                                   const float* __restrict__ mw2,
                                                   const float* __restrict__ mb2,
                                                   float* __restrict__ mech) {
    int wave = (blockIdx.x * 256 + threadIdx.x) >> 6;
    int lane = threadIdx.x & 63;
    const bf16* tr = tin + (size_t)wave * 512;
    float acc = 0.f;
    for (int e = lane; e < 512; e += 64) acc += __bfloat162float(tr[e]) * mw2[e];
#pragma unroll
    for (int off = 32; off; off >>= 1) acc += __shfl_down(acc, off);
    if (lane == 0) mech[wave] = 1.f / (1.f + expf(-(acc + mb2[0])));
}

// ---------------------------------------------------------------------------
// MFMA flash attention (T14 async-STAGE + T13 defer-max + 8-wave, unchanged)
// ---------------------------------------------------------------------------
__global__ __launch_bounds__(512) void attn_mfma_k(
    const bf16* __restrict__ qg,
    const bf16* __restrict__ kg,
    const bf16* __restrict__ vT,
    const float* __restrict__ mech,
    bf16* __restrict__ ctx)
{
    const int bid = blockIdx.x;
    const int qt = bid & 7;
    const int h  = (bid >> 3) & 15;
    const int b  = bid >> 7;
    __shared__ short sK[64 * 72];
    __shared__ short sV[64 * 72];
    __shared__ short sP[8 * 16 * 72];
    __shared__ float sMall[1024];
    const int t = threadIdx.x;
    const int lane = t & 63;
    const int w = t >> 6;
    const int ql = lane & 15;
    const int g = lane >> 4;

    const int qrow = qt * 128 + w * 16 + ql;
    const bf16* qp = qg + ((size_t)(b * 1024 + qrow)) * 1024 + h * 64;
    const short8v qf0 = *(const short8v*)(qp + g * 8);
    const short8v qf1 = *(const short8v*)(qp + 32 + g * 8);

    for (int i = t; i < 1024; i += 512)
        sMall[i] = 0.125f * (1.f + mech[b * 1024 + i]);

    f32x4 O[4] = {};
    float m = -1e30f, l = 0.f;

    const int r0 = t >> 3, c0 = (t & 7) * 8;
    const bf16* kbase = kg + ((size_t)(b * 1024)) * 1024 + h * 64;
    const bf16* vbase = vT + ((size_t)(h * 64)) * 8192 + b * 1024;
    short* pw = &sP[w * 1152];

    short8v kv0 = *(const short8v*)(kbase + (size_t)(r0) * 1024 + c0);
    short8v vv0 = *(const short8v*)(vbase + (size_t)r0 * 8192 + c0);

    for (int kt = 0; kt < 16; ++kt) {
        __builtin_amdgcn_s_barrier();
        *(short8v*)&sK[r0 * 72 + c0] = kv0;
        *(short8v*)&sV[r0 * 72 + c0] = vv0;
        {
            int ktn = (kt + 1 < 16) ? kt + 1 : 15;
            kv0 = *(const short8v*)(kbase + (size_t)(ktn * 64 + r0) * 1024 + c0);
            vv0 = *(const short8v*)(vbase + (size_t)r0 * 8192 + ktn * 64 + c0);
        }
        asm volatile("s_waitcnt lgkmcnt(0)" ::: "memory");
        __builtin_amdgcn_sched_barrier(0);
        __builtin_amdgcn_s_barrier();

        f32x4 sc[4] = {};
#pragma unroll
        for (int su = 0; su < 4; ++su) {
            short8v a0 = *(const short8v*)&sK[(su * 16 + ql) * 72 + g * 8];
            short8v a1 = *(const short8v*)&sK[(su * 16 + ql) * 72 + 32 + g * 8];
            sc[su] = __builtin_amdgcn_mfma_f32_16x16x32_bf16(a0, qf0, sc[su], 0, 0, 0);
            sc[su] = __builtin_amdgcn_mfma_f32_16x16x32_bf16(a1, qf1, sc[su], 0, 0, 0);
        }

        float sv[4][4];
        float mx = -1e30f;
#pragma unroll
        for (int su = 0; su < 4; ++su) {
            f32x4 mv = *(const f32x4*)&sMall[kt * 64 + su * 16 + g * 4];
#pragma unroll
            for (int r = 0; r < 4; ++r) {
                float s = sc[su][r] * mv[r];
                sv[su][r] = s;
                mx = fmaxf(mx, s);
            }
        }
        mx = fmaxf(mx, __shfl_xor(mx, 16));
        mx = fmaxf(mx, __shfl_xor(mx, 32));
        bool nore = __all(mx - m <= 8.f);
        float mn = nore ? m : fmaxf(m, mx);
        float scale = nore ? 1.f : __expf(m - mn);
        m = mn;

        float ps = 0.f;
        uint2 pk[4];
#pragma unroll
        for (int su = 0; su < 4; ++su) {
            float p0 = __expf(sv[su][0] - mn), p1 = __expf(sv[su][1] - mn);
            float p2 = __expf(sv[su][2] - mn), p3 = __expf(sv[su][3] - mn);
            ps += (p0 + p1) + (p2 + p3);
            pk[su].x = (unsigned)bf16bits(p0) | ((unsigned)bf16bits(p1) << 16);
            pk[su].y = (unsigned)bf16bits(p2) | ((unsigned)bf16bits(p3) << 16);
        }
        l = l * scale + ps;

        if (!nore) {
            float os0 = __shfl(scale, g * 4 + 0), os1 = __shfl(scale, g * 4 + 1);
            float os2 = __shfl(scale, g * 4 + 2), os3 = __shfl(scale, g * 4 + 3);
#pragma unroll
            for (int dt = 0; dt < 4; ++dt) {
                O[dt][0] *= os0; O[dt][1] *= os1; O[dt][2] *= os2; O[dt][3] *= os3;
            }
        }

#pragma unroll
        for (int su = 0; su < 4; ++su)
            *(uint2*)&pw[ql * 72 + su * 16 + g * 4] = pk[su];
        asm volatile("s_waitcnt lgkmcnt(0)" ::: "memory");
        __builtin_amdgcn_sched_barrier(0);
        short8v pa0 = *(const short8v*)&pw[ql * 72 + g * 8];
        short8v pa1 = *(const short8v*)&pw[ql * 72 + 32 + g * 8];

#pragma unroll
        for (int dt = 0; dt < 4; ++dt) {
            short8v v0 = *(const short8v*)&sV[(dt * 16 + ql) * 72 + g * 8];
            short8v v1 = *(const short8v*)&sV[(dt * 16 + ql) * 72 + 32 + g * 8];
            O[dt] = __builtin_amdgcn_mfma_f32_16x16x32_bf16(pa0, v0, O[dt], 0, 0, 0);
            O[dt] = __builtin_amdgcn_mfma_f32_16x16x32_bf16(pa1, v1, O[dt], 0, 0, 0);
        }
    }

    l += __shfl_xor(l, 16);
    l += __shfl_xor(l, 32);
    float linv = 1.f / l;
    float ol0 = __shfl(linv, g * 4 + 0), ol1 = __shfl(linv, g * 4 + 1);
    float ol2 = __shfl(linv, g * 4 + 2), ol3 = __shfl(linv, g * 4 + 3);
    bf16* cp = ctx + ((size_t)(b * 1024 + qt * 128 + w * 16)) * 1024 + h * 64;
#pragma unroll
    for (int dt = 0; dt < 4; ++dt) {
        cp[(g * 4 + 0) * 1024 + dt * 16 + ql] = __float2bfloat16(O[dt][0] * ol0);
        cp[(g * 4 + 1) * 1024 + dt * 16 + ql] = __float2bfloat16(O[dt][1] * ol1);
        cp[(g * 4 + 2) * 1024 + dt * 16 + ql] = __float2bfloat16(O[dt][2] * ol2);
        cp[(g * 4 + 3) * 1024 + dt * 16 + ql] = __float2bfloat16(O[dt][3] * ol3);
    }
}

// ---------------------------------------------------------------------------
// launch
// ---------------------------------------------------------------------------
extern "C" void kernel_launch(void* const* d_in, const int* in_sizes, int n_in,
                              void* d_out, int out_size, void* d_ws, size_t ws_size,
                              hipStream_t stream) {
    const float* x         = (const float*)d_in[0];
    const float* pos_table = (const float*)d_in[1];
    const float* time_tab  = (const float*)d_in[2];
    const float* wi        = (const float*)d_in[3];
    const float* bi        = (const float*)d_in[4];
    const float* g1        = (const float*)d_in[5];
    const float* be1       = (const float*)d_in[6];
    const float* g2        = (const float*)d_in[7];
    const float* be2       = (const float*)d_in[8];
    const float* g3        = (const float*)d_in[9];
    const float* be3       = (const float*)d_in[10];
    const float* qw        = (const float*)d_in[11];
    const float* qb        = (const float*)d_in[12];
    const float* kw        = (const float*)d_in[13];
    const float* kb        = (const float*)d_in[14];
    const float* vw        = (const float*)d_in[15];
    const float* vb        = (const float*)d_in[16];
    const float* ow        = (const float*)d_in[17];
    const float* ob        = (const float*)d_in[18];
    const float* mw1       = (const float*)d_in[19];
    const float* mb1       = (const float*)d_in[20];
    const float* mw2       = (const float*)d_in[21];
    const float* mb2       = (const float*)d_in[22];
    const float* ew        = (const float*)d_in[23];
    const float* eb        = (const float*)d_in[24];
    const float* elw       = (const float*)d_in[25];
    const float* fw1       = (const float*)d_in[26];
    const float* fb1       = (const float*)d_in[27];
    const float* fw2       = (const float*)d_in[28];
    const float* fb2       = (const float*)d_in[29];

    float* out = (float*)d_out;
    float* ws  = (float*)d_ws;

    // ws layout (float offsets)
    const size_t XACC  = 0;                    // f32 [8192,1024]
    const size_t HBF   = 8388608;              // bf16 [8192,1024]
    const size_t CQ    = 12582912;             // bf16 q / pe / ffn1 part
    const size_t DK    = 20971520;             // bf16 k / f32 pp / ffn1 part
    const size_t EV    = 29360128;             // bf16 vT, then bf16 P1|P2
    const size_t FC    = 37748736;             // bf16 tmh then bf16 ctx
    const size_t WIT   = 41943040;             // 524288 f each (bf16 1024x1024)
    const size_t QWT   = WIT  + 524288;
    const size_t KWT   = QWT  + 524288;
    const size_t MW1T  = KWT  + 524288;        // 262144 f
    const size_t VWT   = MW1T + 262144;
    const size_t OWT   = VWT  + 524288;
    const size_t W5T   = OWT  + 524288;
    const size_t FW1T  = W5T  + 524288;        // 2097152 f
    const size_t FW2T  = FW1T + 2097152;       // 2097152 f
    const size_t B5    = FW2T + 2097152;       // 1024 f
    const size_t W5S   = B5   + 1024;          // 8 f
    const size_t CATB  = W5S  + 8;             // 2560 f
    const size_t WS_FLOATS = CATB + 2560;      // ~198 MB
    if (ws_size < WS_FLOATS * sizeof(float)) return;

    float* xacc = ws + XACC;
    bf16*  h_bf = (bf16*)(ws + HBF);
    bf16*  q_bf = (bf16*)(ws + CQ);
    bf16*  k_bf = (bf16*)(ws + DK);
    bf16*  vTb  = (bf16*)(ws + EV);
    bf16*  pe   = (bf16*)(ws + CQ);    // dead before q written
    float* pp   = ws + DK;             // dead before k written
    bf16*  tmh  = (bf16*)(ws + FC);
    bf16*  ctxb = (bf16*)(ws + FC);
    bf16*  ffn1 = (bf16*)(ws + CQ);
    bf16*  P1   = (bf16*)(ws + EV);              // aliases dead vT
    bf16*  P2   = (bf16*)(ws + EV + 4194304);

    bf16* wiT  = (bf16*)(ws + WIT);
    bf16* qwT  = (bf16*)(ws + QWT);
    bf16* kwT  = (bf16*)(ws + KWT);
    bf16* mw1T = (bf16*)(ws + MW1T);
    bf16* vwT  = (bf16*)(ws + VWT);
    bf16* owT  = (bf16*)(ws + OWT);
    bf16* w5T  = (bf16*)(ws + W5T);
    bf16* fw1T = (bf16*)(ws + FW1T);
    bf16* fw2T = (bf16*)(ws + FW2T);
    float* b5  = ws + B5;
    float* w5s = ws + W5S;
    float* catb = ws + CATB;

    float* mech = out + 8388608;
    float* wout = out + 8396800;

    // --- weight prep ---
    prep_k<<<14, 256, 0, stream>>>(elw, eb, qb, kb, mb1, wout, w5s, b5, catb);
    combine_ewT_k<<<dim3(32, 32), 256, 0, stream>>>(ew, w5s, w5T);
    tconv5_k<<<dim3(32, 32, 5), 256, 0, stream>>>(wi, qw, kw, vw, ow,
                                                  wiT, qwT, kwT, vwT, owT);
    tconv_k<<<dim3(32, 16), 256, 0, stream>>>(mw1, mw1T, 1024, 512);
    tconv_k<<<dim3(32, 128), 256, 0, stream>>>(fw1, fw1T, 1024, 4096);
    tconv_k<<<dim3(128, 32), 256, 0, stream>>>(fw2, fw2T, 4096, 1024);

    // --- position/timing: pp = pe@wiT + bi, then fused add+LN1 ---
    build_pe_k<<<4096, 256, 0, stream>>>(pos_table, time_tab, pe);
    gemm_ring<0,false><<<64, 256, 0, stream>>>(pe, wiT, bi, nullptr,
                                               pp, nullptr, nullptr, 1024, 1024, 1024, 1024);
    layernorm_pe_k<<<NROWS, 256, 0, stream>>>(x, pp, g1, be1, xacc, h_bf);

    // --- attention block ---
    gemm_ring<3,false><<<1280, 256, 0, stream>>>(h_bf, qwT, catb, nullptr,
                                                 q_bf, k_bf, tmh, NROWS, 2560, 1024, 1024);
    gemm_ring<4,false><<<512, 256, 0, stream>>>(vwT, h_bf, vb, nullptr,
                                                vTb, nullptr, nullptr, 1024, 8192, 1024, 1024);
    mech_head_k<<<2048, 256, 0, stream>>>(tmh, mw2, mb2, mech);

    attn_mfma_k<<<1024, 512, 0, stream>>>(q_bf, k_bf, vTb, mech, ctxb);
    gemm_ring<0,false><<<512, 256, 0, stream>>>(ctxb, owT, ob, xacc,
                                                xacc, nullptr, nullptr, NROWS, 1024, 1024, 1024);

    // --- five elements ---
    layernorm_k<<<NROWS, 256, 0, stream>>>(xacc, g2, be2, h_bf);
    gemm_ring<0,false><<<512, 256, 0, stream>>>(h_bf, w5T, b5, xacc,
                                                xacc, nullptr, nullptr, NROWS, 1024, 1024, 1024);

    // --- FFN ---
    layernorm_k<<<NROWS, 256, 0, stream>>>(xacc, g3, be3, h_bf);
    gemm_ring<2,false><<<2048, 256, 0, stream>>>(h_bf, fw1T, fb1, nullptr,
                                                 ffn1, nullptr, nullptr, NROWS, DFFN, 1024, 1024);
    // FFN2 split-K x2: halves run in one 1024-block dispatch (4 blocks/CU),
    // bf16 partials into P1/P2 (alias dead vT), then combine with bias+residual.
    gemm_ring<6,true><<<1024, 256, 0, stream>>>(ffn1, fw2T, nullptr, nullptr,
                                                P1, P2, nullptr, NROWS, 1024, 2048, DFFN);
    combine_ffn2_k<<<8192, 256, 0, stream>>>(xacc, fb2, P1, P2, out);
}

// Round 14
// 533.499 us; speedup vs baseline: 1.0331x; 1.0331x over previous
//
#include <hip/hip_runtime.h>
#include <hip/hip_bf16.h>
#include <math.h>

// Problem constants
#define BB 8
#define SS 1024
#define DD 1024
#define HH 16
#define DHH 64
#define DFFN 4096
#define NROWS (BB*SS)   // 8192

typedef __attribute__((ext_vector_type(8))) short short8v;  // 8 bf16 (4 VGPRs)
typedef __attribute__((ext_vector_type(4))) float f32x4;
typedef __hip_bfloat16 bf16;

__device__ __forceinline__ float gelu_f(float x) {
    return 0.5f * x * (1.0f + erff(x * 0.70710678118654752440f));
}
__device__ __forceinline__ unsigned short bf16bits(float x) {
    bf16 h = __float2bfloat16(x);
    return *reinterpret_cast<unsigned short*>(&h);
}

#define AS1C const __attribute__((address_space(1))) void*
#define AS3P __attribute__((address_space(3))) void*
#define GLDS16(g, l) __builtin_amdgcn_global_load_lds((AS1C)(g), (AS3P)(l), 16, 0, 0)

// ---------------------------------------------------------------------------
// prep: w=softmax(elw) (block0 writes), b5 = sum_p w_p*eb[p] (blocks 0-3),
//       catb = qb|kb|mb1 (blocks 4-13). One launch.
// ---------------------------------------------------------------------------
__global__ __launch_bounds__(256) void prep_k(const float* __restrict__ elw,
                                              const float* __restrict__ eb,
                                              const float* __restrict__ qb,
                                              const float* __restrict__ kb,
                                              const float* __restrict__ mb1,
                                              float* __restrict__ w_out,
                                              float* __restrict__ w_ws,
                                              float* __restrict__ b5,
                                              float* __restrict__ catb) {
    int t = threadIdx.x, blk = blockIdx.x;
    float e0 = elw[0], e1 = elw[1], e2 = elw[2], e3 = elw[3], e4 = elw[4];
    float mx = fmaxf(fmaxf(fmaxf(e0, e1), fmaxf(e2, e3)), e4);
    float x0 = expf(e0 - mx), x1 = expf(e1 - mx), x2 = expf(e2 - mx),
          x3 = expf(e3 - mx), x4 = expf(e4 - mx);
    float inv = 1.f / (x0 + x1 + x2 + x3 + x4);
    float w[5] = {x0 * inv, x1 * inv, x2 * inv, x3 * inv, x4 * inv};
    if (blk == 0 && t < 5) { w_out[t] = w[t]; w_ws[t] = w[t]; }
    if (blk < 4) {
        int i = blk * 256 + t;
        float acc = 0.f;
#pragma unroll
        for (int p = 0; p < 5; ++p) acc += w[p] * eb[p * DD + i];
        b5[i] = acc;
    } else {
        int i = (blk - 4) * 256 + t;
        if (i < 2560) {
            float v = (i < 1024) ? qb[i] : (i < 2048) ? kb[i - 1024] : mb1[i - 2048];
            catb[i] = v;
        }
    }
}

// ---------------------------------------------------------------------------
// combine_ewT: w5T[e][d] = bf16( sum_p w_p * ew[p][d][e] )
// ---------------------------------------------------------------------------
__global__ __launch_bounds__(256) void combine_ewT_k(const float* __restrict__ ew,
                                                     const float* __restrict__ w_ws,
                                                     bf16* __restrict__ w5T) {
    __shared__ float tile[32][33];
    float w0 = w_ws[0], w1 = w_ws[1], w2 = w_ws[2], w3 = w_ws[3], w4 = w_ws[4];
    int d0 = blockIdx.x * 32, e0 = blockIdx.y * 32;
    int tx = threadIdx.x & 31, ty = threadIdx.x >> 5;   // 32 x 8
#pragma unroll
    for (int i = 0; i < 32; i += 8) {
        size_t off = (size_t)(d0 + ty + i) * 1024 + e0 + tx;
        float acc = w0 * ew[off] + w1 * ew[1048576 + off] + w2 * ew[2097152 + off]
                  + w3 * ew[3145728 + off] + w4 * ew[4194304 + off];
        tile[ty + i][tx] = acc;
    }
    __syncthreads();
#pragma unroll
    for (int i = 0; i < 32; i += 8)
        w5T[(size_t)(e0 + ty + i) * 1024 + d0 + tx] = __float2bfloat16(tile[tx][ty + i]);
}

// ---------------------------------------------------------------------------
// tconv: in f32 [K,N] -> out bf16 [N,K]  (generic)
// ---------------------------------------------------------------------------
__global__ __launch_bounds__(256) void tconv_k(const float* __restrict__ in,
                                               bf16* __restrict__ out,
                                               int K, int N) {
    __shared__ float tile[32][33];
    int k0 = blockIdx.x * 32, n0 = blockIdx.y * 32;
    int tx = threadIdx.x & 31, ty = threadIdx.x >> 5;   // 32 x 8
#pragma unroll
    for (int i = 0; i < 32; i += 8)
        tile[ty + i][tx] = in[(size_t)(k0 + ty + i) * N + n0 + tx];
    __syncthreads();
#pragma unroll
    for (int i = 0; i < 32; i += 8)
        out[(size_t)(n0 + ty + i) * K + k0 + tx] = __float2bfloat16(tile[tx][ty + i]);
}

// ---------------------------------------------------------------------------
// tconv5: five 1024x1024 f32->bf16 transposes in one launch
// ---------------------------------------------------------------------------
__global__ __launch_bounds__(256) void tconv5_k(
    const float* __restrict__ s0, const float* __restrict__ s1,
    const float* __restrict__ s2, const float* __restrict__ s3,
    const float* __restrict__ s4,
    bf16* __restrict__ d0, bf16* __restrict__ d1, bf16* __restrict__ d2,
    bf16* __restrict__ d3, bf16* __restrict__ d4) {
    const float* in; bf16* out;
    switch (blockIdx.z) {
        case 0: in = s0; out = d0; break;
        case 1: in = s1; out = d1; break;
        case 2: in = s2; out = d2; break;
        case 3: in = s3; out = d3; break;
        default: in = s4; out = d4; break;
    }
    __shared__ float tile[32][33];
    int k0 = blockIdx.x * 32, n0 = blockIdx.y * 32;
    int tx = threadIdx.x & 31, ty = threadIdx.x >> 5;   // 32 x 8
#pragma unroll
    for (int i = 0; i < 32; i += 8)
        tile[ty + i][tx] = in[(size_t)(k0 + ty + i) * 1024 + n0 + tx];
    __syncthreads();
#pragma unroll
    for (int i = 0; i < 32; i += 8)
        out[(size_t)(n0 + ty + i) * 1024 + k0 + tx] = __float2bfloat16(tile[tx][ty + i]);
}

// ---------------------------------------------------------------------------
// build_pe (bf16)
// ---------------------------------------------------------------------------
__global__ __launch_bounds__(256) void build_pe_k(const float* __restrict__ pos,
                                                  const float* __restrict__ tim,
                                                  bf16* __restrict__ pe) {
    int idx = blockIdx.x * 256 + threadIdx.x;   // over 1048576
    int s = idx >> 10, d = idx & 1023;
    float v = (d < 512) ? pos[s * 512 + d] : tim[s * 512 + (d - 512)];
    pe[idx] = __float2bfloat16(v);
}

// ---------------------------------------------------------------------------
// add_pe: xacc = x + pp[s]  (broadcast over batch, full-chip parallelism).
// Round-11 lesson: fusing this into the 64-block pe-GEMM epilogue ran the
// 64 MB broadcast at 1/4-chip parallelism -> 235us. Round-13 lesson: fusing
// into LN1 + split-K FFN2 was also net negative. Keep it separate.
// ---------------------------------------------------------------------------
__global__ __launch_bounds__(256) void add_pe_k(const float4* __restrict__ x,
                                                const float4* __restrict__ pp,
                                                float4* __restrict__ xo) {
    int idx = blockIdx.x * 256 + threadIdx.x;   // over 2097152
    int sd = idx & (262144 - 1);                // (S*D)/4
    float4 a = x[idx], b = pp[sd];
    xo[idx] = make_float4(a.x + b.x, a.y + b.y, a.z + b.z, a.w + b.w);
}

// ---------------------------------------------------------------------------
// layernorm (bf16 out)
// ---------------------------------------------------------------------------
__global__ __launch_bounds__(256) void layernorm_k(const float* __restrict__ in,
                                                   const float* __restrict__ g,
                                                   const float* __restrict__ be,
                                                   bf16* __restrict__ out) {
    int row = blockIdx.x;
    int t = threadIdx.x;
    const float* x = in + (size_t)row * DD;
    float4 xv = *reinterpret_cast<const float4*>(&x[t * 4]);
    float s  = xv.x + xv.y + xv.z + xv.w;
    float ss = xv.x * xv.x + xv.y * xv.y + xv.z * xv.z + xv.w * xv.w;
#pragma unroll
    for (int off = 32; off; off >>= 1) {
        s  += __shfl_down(s, off);
        ss += __shfl_down(ss, off);
    }
    __shared__ float sm[4], sv[4], stats[2];
    int w = t >> 6;
    if ((t & 63) == 0) { sm[w] = s; sv[w] = ss; }
    __syncthreads();
    if (t == 0) {
        float S1 = sm[0] + sm[1] + sm[2] + sm[3];
        float S2 = sv[0] + sv[1] + sv[2] + sv[3];
        float mean = S1 * (1.f / (float)DD);
        float var  = S2 * (1.f / (float)DD) - mean * mean;
        stats[0] = mean;
        stats[1] = rsqrtf(var + 1e-5f);
    }
    __syncthreads();
    float mean = stats[0], inv = stats[1];
    float4 gv = *reinterpret_cast<const float4*>(&g[t * 4]);
    float4 bv = *reinterpret_cast<const float4*>(&be[t * 4]);
    union { bf16 h[4]; uint2 u; } pk;
    pk.h[0] = __float2bfloat16((xv.x - mean) * inv * gv.x + bv.x);
    pk.h[1] = __float2bfloat16((xv.y - mean) * inv * gv.y + bv.y);
    pk.h[2] = __float2bfloat16((xv.z - mean) * inv * gv.z + bv.z);
    pk.h[3] = __float2bfloat16((xv.w - mean) * inv * gv.w + bv.w);
    *reinterpret_cast<uint2*>(&out[(size_t)row * DD + t * 4]) = pk.u;
}

// ---------------------------------------------------------------------------
// Ring MFMA GEMM v4.1 (round-12 best config): 2-slot double buffer, 4
// blocks/CU, pointer-increment staging, XOR swizzle (0 conflicts),
// XCD-contiguous + group-M(8) ordering.
// OUTMODE: 0=f32 +bias(col)+res; 2=bf16 gelu(x+bias);
//          3=qkm split (q,k bf16; mech gelu bf16); 4=bf16 +bias(row)
// ---------------------------------------------------------------------------
template <int OUTMODE>
__global__ __launch_bounds__(256, 4) void gemm_ring(
    const bf16* __restrict__ A, const bf16* __restrict__ BT,
    const float* __restrict__ bias, const float* __restrict__ res,
    void* __restrict__ C0, void* __restrict__ C1, void* __restrict__ C2,
    int M, int N, int K)
{
    constexpr int BM = 128, BN = 128;
    constexpr int SLOTB = (BM + BN) * 64;      // 16 KB per slot (A then B)
    __shared__ char lds[2 * SLOTB];            // 32 KB
    const int tid = threadIdx.x, lane = tid & 63, wid = tid >> 6;
    const int ql = lane & 15, g = lane >> 4;
    const int wr = wid >> 1, wc = wid & 1;

    // XCD-contiguous chunks, then group-M(8) ordering for L2 reuse
    const int nby = N / BN;
    int b0 = blockIdx.x, nwg = gridDim.x;
    int id = (b0 & 7) * (nwg >> 3) + (b0 >> 3);   // same-XCD ids contiguous
    const int gsz = 8 * nby;                       // GM=8 tiles per group
    int grp = id / gsz, rem = id % gsz;
    const int bm = (grp * 8 + (rem & 7)) * BM;     // nbx % 8 == 0 for all launches
    const int bn = (rem >> 3) * BN;

    // staging: 128-row panel = 512 x 16B chunks; 256 threads -> 2 loads/panel.
    // chunk c of row r holds global chunk c ^ ((r>>1)&3)  (inverse-swizzled src)
    const int id0 = tid, id1 = tid + 256;
    const int ra0 = id0 >> 2, ca0 = id0 & 3;
    const int ra1 = id1 >> 2, ca1 = id1 & 3;
    const bf16* ga0 = A  + (size_t)(bm + ra0) * K + ((ca0 ^ ((ra0 >> 1) & 3)) * 8);
    const bf16* ga1 = A  + (size_t)(bm + ra1) * K + ((ca1 ^ ((ra1 >> 1) & 3)) * 8);
    const bf16* gb0 = BT + (size_t)(bn + ra0) * K + ((ca0 ^ ((ra0 >> 1) & 3)) * 8);
    const bf16* gb1 = BT + (size_t)(bn + ra1) * K + ((ca1 ^ ((ra1 >> 1) & 3)) * 8);

    // fragment LDS byte offsets (within slot), swizzled on read side
    int aoff[4], boff[4];
#pragma unroll
    for (int i = 0; i < 4; ++i) {
        int row = wr * 64 + i * 16 + ql;
        aoff[i] = row * 64 + ((g ^ ((row >> 1) & 3)) * 16);
        int brow = wc * 64 + i * 16 + ql;
        boff[i] = BM * 64 + brow * 64 + ((g ^ ((brow >> 1) & 3)) * 16);
    }

    const int NT = K >> 5;
    auto STAGE = [&](int slot) {
        char* base = lds + slot * SLOTB;
        GLDS16(ga0, base + tid * 16);
        GLDS16(ga1, base + 4096 + tid * 16);
        GLDS16(gb0, base + 8192 + tid * 16);
        GLDS16(gb1, base + 12288 + tid * 16);
        ga0 += 32; ga1 += 32; gb0 += 32; gb1 += 32;
    };

    f32x4 acc[4][4] = {};
    STAGE(0);
    for (int t = 0; t < NT; ++t) {
        asm volatile("s_waitcnt vmcnt(0)" ::: "memory");   // tile t landed
        __builtin_amdgcn_s_barrier();
        __builtin_amdgcn_sched_barrier(0);
        if (t + 1 < NT) STAGE((t + 1) & 1);
        __builtin_amdgcn_sched_barrier(0);
        char* slot = lds + (t & 1) * SLOTB;
        short8v af[4], bfr[4];
#pragma unroll
        for (int i = 0; i < 4; ++i) af[i]  = *(const short8v*)(slot + aoff[i]);
#pragma unroll
        for (int j = 0; j < 4; ++j) bfr[j] = *(const short8v*)(slot + boff[j]);
        __builtin_amdgcn_s_setprio(1);
#pragma unroll
        for (int i = 0; i < 4; ++i)
#pragma unroll
            for (int j = 0; j < 4; ++j)
                acc[i][j] = __builtin_amdgcn_mfma_f32_16x16x32_bf16(af[i], bfr[j], acc[i][j], 0, 0, 0);
        __builtin_amdgcn_s_setprio(0);
    }

    // epilogue: C/D layout col=lane&15, row=(lane>>4)*4+reg
    const int colbase = bn + wc * 64 + ql;
    const int rowbase = bm + wr * 64 + g * 4;
#pragma unroll
    for (int j = 0; j < 4; ++j) {
        int col = colbase + j * 16;
#pragma unroll
        for (int i = 0; i < 4; ++i) {
#pragma unroll
            for (int r = 0; r < 4; ++r) {
                int row = rowbase + i * 16 + r;
                float val = acc[i][j][r];
                if (OUTMODE == 0) {
                    val += bias[col];
                    if (res) val += res[(size_t)row * N + col];
                    ((float*)C0)[(size_t)row * N + col] = val;
                } else if (OUTMODE == 2) {
                    val = gelu_f(val + bias[col]);
                    ((bf16*)C0)[(size_t)row * N + col] = __float2bfloat16(val);
                } else if (OUTMODE == 3) {
                    val += bias[col];
                    if (col < 1024)
                        ((bf16*)C0)[(size_t)row * 1024 + col] = __float2bfloat16(val);
                    else if (col < 2048)
                        ((bf16*)C1)[(size_t)row * 1024 + (col - 1024)] = __float2bfloat16(val);
                    else
                        ((bf16*)C2)[(size_t)row * 512 + (col - 2048)] = __float2bfloat16(gelu_f(val));
                } else {   // 4: bias per row, bf16
                    val += bias[row];
                    ((bf16*)C0)[(size_t)row * N + col] = __float2bfloat16(val);
                }
            }
        }
    }
}

// ---------------------------------------------------------------------------
// mech head
// ---------------------------------------------------------------------------
__global__ __launch_bounds__(256) void mech_head_k(const bf16* __restrict__ tin,
                                                   const float* __restrict__ mw2,
                                                   const float* __restrict__ mb2,
                                                   float* __restrict__ mech) {
    int wave = (blockIdx.x * 256 + threadIdx.x) >> 6;
    int lane = threadIdx.x & 63;
    const bf16* tr = tin + (size_t)wave * 512;
    float acc = 0.f;
    for (int e = lane; e < 512; e += 64) acc += __bfloat162float(tr[e]) * mw2[e];
#pragma unroll
    for (int off = 32; off; off >>= 1) acc += __shfl_down(acc, off);
    if (lane == 0) mech[wave] = 1.f / (1.f + expf(-(acc + mb2[0])));
}

// ---------------------------------------------------------------------------
// MFMA flash attention (T14 async-STAGE + T13 defer-max + 8-wave; round-12)
// ---------------------------------------------------------------------------
__global__ __launch_bounds__(512) void attn_mfma_k(
    const bf16* __restrict__ qg,
    const bf16* __restrict__ kg,
    const bf16* __restrict__ vT,
    const float* __restrict__ mech,
    bf16* __restrict__ ctx)
{
    const int bid = blockIdx.x;
    const int qt = bid & 7;              // 8 tiles of 128 q-rows
    const int h  = (bid >> 3) & 15;
    const int b  = bid >> 7;
    __shared__ short sK[64 * 72];
    __shared__ short sV[64 * 72];
    __shared__ short sP[8 * 16 * 72];
    __shared__ float sMall[1024];
    const int t = threadIdx.x;
    const int lane = t & 63;
    const int w = t >> 6;                // 8 waves
    const int ql = lane & 15;
    const int g = lane >> 4;

    const int qrow = qt * 128 + w * 16 + ql;
    const bf16* qp = qg + ((size_t)(b * 1024 + qrow)) * 1024 + h * 64;
    const short8v qf0 = *(const short8v*)(qp + g * 8);
    const short8v qf1 = *(const short8v*)(qp + 32 + g * 8);

    for (int i = t; i < 1024; i += 512)
        sMall[i] = 0.125f * (1.f + mech[b * 1024 + i]);

    f32x4 O[4] = {};
    float m = -1e30f, l = 0.f;

    const int r0 = t >> 3, c0 = (t & 7) * 8;
    const bf16* kbase = kg + ((size_t)(b * 1024)) * 1024 + h * 64;
    const bf16* vbase = vT + ((size_t)(h * 64)) * 8192 + b * 1024;
    short* pw = &sP[w * 1152];

    short8v kv0 = *(const short8v*)(kbase + (size_t)(r0) * 1024 + c0);
    short8v vv0 = *(const short8v*)(vbase + (size_t)r0 * 8192 + c0);

    for (int kt = 0; kt < 16; ++kt) {
        __builtin_amdgcn_s_barrier();          // all waves done reading LDS
        *(short8v*)&sK[r0 * 72 + c0] = kv0;
        *(short8v*)&sV[r0 * 72 + c0] = vv0;
        {
            int ktn = (kt + 1 < 16) ? kt + 1 : 15;
            kv0 = *(const short8v*)(kbase + (size_t)(ktn * 64 + r0) * 1024 + c0);
            vv0 = *(const short8v*)(vbase + (size_t)r0 * 8192 + ktn * 64 + c0);
        }
        asm volatile("s_waitcnt lgkmcnt(0)" ::: "memory");
        __builtin_amdgcn_sched_barrier(0);
        __builtin_amdgcn_s_barrier();

        f32x4 sc[4] = {};
#pragma unroll
        for (int su = 0; su < 4; ++su) {
            short8v a0 = *(const short8v*)&sK[(su * 16 + ql) * 72 + g * 8];
            short8v a1 = *(const short8v*)&sK[(su * 16 + ql) * 72 + 32 + g * 8];
            sc[su] = __builtin_amdgcn_mfma_f32_16x16x32_bf16(a0, qf0, sc[su], 0, 0, 0);
            sc[su] = __builtin_amdgcn_mfma_f32_16x16x32_bf16(a1, qf1, sc[su], 0, 0, 0);
        }

        float sv[4][4];
        float mx = -1e30f;
#pragma unroll
        for (int su = 0; su < 4; ++su) {
            f32x4 mv = *(const f32x4*)&sMall[kt * 64 + su * 16 + g * 4];
#pragma unroll
            for (int r = 0; r < 4; ++r) {
                float s = sc[su][r] * mv[r];
                sv[su][r] = s;
                mx = fmaxf(mx, s);
            }
        }
        mx = fmaxf(mx, __shfl_xor(mx, 16));
        mx = fmaxf(mx, __shfl_xor(mx, 32));
        // T13 defer-max: keep old m when tile max within 8 (wave-uniform)
        bool nore = __all(mx - m <= 8.f);
        float mn = nore ? m : fmaxf(m, mx);
        float scale = nore ? 1.f : __expf(m - mn);
        m = mn;

        float ps = 0.f;
        uint2 pk[4];
#pragma unroll
        for (int su = 0; su < 4; ++su) {
            float p0 = __expf(sv[su][0] - mn), p1 = __expf(sv[su][1] - mn);
            float p2 = __expf(sv[su][2] - mn), p3 = __expf(sv[su][3] - mn);
            ps += (p0 + p1) + (p2 + p3);
            pk[su].x = (unsigned)bf16bits(p0) | ((unsigned)bf16bits(p1) << 16);
            pk[su].y = (unsigned)bf16bits(p2) | ((unsigned)bf16bits(p3) << 16);
        }
        l = l * scale + ps;

        if (!nore) {
            float os0 = __shfl(scale, g * 4 + 0), os1 = __shfl(scale, g * 4 + 1);
            float os2 = __shfl(scale, g * 4 + 2), os3 = __shfl(scale, g * 4 + 3);
#pragma unroll
            for (int dt = 0; dt < 4; ++dt) {
                O[dt][0] *= os0; O[dt][1] *= os1; O[dt][2] *= os2; O[dt][3] *= os3;
            }
        }

#pragma unroll
        for (int su = 0; su < 4; ++su)
            *(uint2*)&pw[ql * 72 + su * 16 + g * 4] = pk[su];
        asm volatile("s_waitcnt lgkmcnt(0)" ::: "memory");
        __builtin_amdgcn_sched_barrier(0);
        short8v pa0 = *(const short8v*)&pw[ql * 72 + g * 8];
        short8v pa1 = *(const short8v*)&pw[ql * 72 + 32 + g * 8];

#pragma unroll
        for (int dt = 0; dt < 4; ++dt) {
            short8v v0 = *(const short8v*)&sV[(dt * 16 + ql) * 72 + g * 8];
            short8v v1 = *(const short8v*)&sV[(dt * 16 + ql) * 72 + 32 + g * 8];
            O[dt] = __builtin_amdgcn_mfma_f32_16x16x32_bf16(pa0, v0, O[dt], 0, 0, 0);
            O[dt] = __builtin_amdgcn_mfma_f32_16x16x32_bf16(pa1, v1, O[dt], 0, 0, 0);
        }
    }

    l += __shfl_xor(l, 16);
    l += __shfl_xor(l, 32);
    float linv = 1.f / l;
    float ol0 = __shfl(linv, g * 4 + 0), ol1 = __shfl(linv, g * 4 + 1);
    float ol2 = __shfl(linv, g * 4 + 2), ol3 = __shfl(linv, g * 4 + 3);
    bf16* cp = ctx + ((size_t)(b * 1024 + qt * 128 + w * 16)) * 1024 + h * 64;
#pragma unroll
    for (int dt = 0; dt < 4; ++dt) {
        cp[(g * 4 + 0) * 1024 + dt * 16 + ql] = __float2bfloat16(O[dt][0] * ol0);
        cp[(g * 4 + 1) * 1024 + dt * 16 + ql] = __float2bfloat16(O[dt][1] * ol1);
        cp[(g * 4 + 2) * 1024 + dt * 16 + ql] = __float2bfloat16(O[dt][2] * ol2);
        cp[(g * 4 + 3) * 1024 + dt * 16 + ql] = __float2bfloat16(O[dt][3] * ol3);
    }
}

// ---------------------------------------------------------------------------
// launch
// ---------------------------------------------------------------------------
extern "C" void kernel_launch(void* const* d_in, const int* in_sizes, int n_in,
                              void* d_out, int out_size, void* d_ws, size_t ws_size,
                              hipStream_t stream) {
    const float* x         = (const float*)d_in[0];
    const float* pos_table = (const float*)d_in[1];
    const float* time_tab  = (const float*)d_in[2];
    const float* wi        = (const float*)d_in[3];
    const float* bi        = (const float*)d_in[4];
    const float* g1        = (const float*)d_in[5];
    const float* be1       = (const float*)d_in[6];
    const float* g2        = (const float*)d_in[7];
    const float* be2       = (const float*)d_in[8];
    const float* g3        = (const float*)d_in[9];
    const float* be3       = (const float*)d_in[10];
    const float* qw        = (const float*)d_in[11];
    const float* qb        = (const float*)d_in[12];
    const float* kw        = (const float*)d_in[13];
    const float* kb        = (const float*)d_in[14];
    const float* vw        = (const float*)d_in[15];
    const float* vb        = (const float*)d_in[16];
    const float* ow        = (const float*)d_in[17];
    const float* ob        = (const float*)d_in[18];
    const float* mw1       = (const float*)d_in[19];
    const float* mb1       = (const float*)d_in[20];
    const float* mw2       = (const float*)d_in[21];
    const float* mb2       = (const float*)d_in[22];
    const float* ew        = (const float*)d_in[23];
    const float* eb        = (const float*)d_in[24];
    const float* elw       = (const float*)d_in[25];
    const float* fw1       = (const float*)d_in[26];
    const float* fb1       = (const float*)d_in[27];
    const float* fw2       = (const float*)d_in[28];
    const float* fb2       = (const float*)d_in[29];

    float* out = (float*)d_out;
    float* ws  = (float*)d_ws;

    // ws layout (float offsets)
    const size_t XACC  = 0;                    // f32 [8192,1024]
    const size_t HBF   = 8388608;              // bf16 [8192,1024]
    const size_t CQ    = 12582912;             // bf16 q / pe / ffn1 part
    const size_t DK    = 20971520;             // bf16 k / f32 pp / ffn1 part
    const size_t EV    = 29360128;             // bf16 vT
    const size_t FC    = 37748736;             // bf16 tmh then bf16 ctx
    const size_t WIT   = 41943040;             // 524288 f each (bf16 1024x1024)
    const size_t QWT   = WIT  + 524288;
    const size_t KWT   = QWT  + 524288;
    const size_t MW1T  = KWT  + 524288;        // 262144 f
    const size_t VWT   = MW1T + 262144;
    const size_t OWT   = VWT  + 524288;
    const size_t W5T   = OWT  + 524288;
    const size_t FW1T  = W5T  + 524288;        // 2097152 f
    const size_t FW2T  = FW1T + 2097152;       // 2097152 f
    const size_t B5    = FW2T + 2097152;       // 1024 f
    const size_t W5S   = B5   + 1024;          // 8 f
    const size_t CATB  = W5S  + 8;             // 2560 f
    const size_t WS_FLOATS = CATB + 2560;      // ~198 MB
    if (ws_size < WS_FLOATS * sizeof(float)) return;

    float* xacc = ws + XACC;
    bf16*  h_bf = (bf16*)(ws + HBF);
    bf16*  q_bf = (bf16*)(ws + CQ);
    bf16*  k_bf = (bf16*)(ws + DK);
    bf16*  vTb  = (bf16*)(ws + EV);
    bf16*  pe   = (bf16*)(ws + CQ);    // dead before q written
    float* pp   = ws + DK;             // dead before k written
    bf16*  tmh  = (bf16*)(ws + FC);
    bf16*  ctxb = (bf16*)(ws + FC);
    bf16*  ffn1 = (bf16*)(ws + CQ);

    bf16* wiT  = (bf16*)(ws + WIT);
    bf16* qwT  = (bf16*)(ws + QWT);
    bf16* kwT  = (bf16*)(ws + KWT);
    bf16* mw1T = (bf16*)(ws + MW1T);
    bf16* vwT  = (bf16*)(ws + VWT);
    bf16* owT  = (bf16*)(ws + OWT);
    bf16* w5T  = (bf16*)(ws + W5T);
    bf16* fw1T = (bf16*)(ws + FW1T);
    bf16* fw2T = (bf16*)(ws + FW2T);
    float* b5  = ws + B5;
    float* w5s = ws + W5S;
    float* catb = ws + CATB;

    float* mech = out + 8388608;
    float* wout = out + 8396800;

    // --- weight prep ---
    prep_k<<<14, 256, 0, stream>>>(elw, eb, qb, kb, mb1, wout, w5s, b5, catb);
    combine_ewT_k<<<dim3(32, 32), 256, 0, stream>>>(ew, w5s, w5T);
    tconv5_k<<<dim3(32, 32, 5), 256, 0, stream>>>(wi, qw, kw, vw, ow,
                                                  wiT, qwT, kwT, vwT, owT);
    tconv_k<<<dim3(32, 16), 256, 0, stream>>>(mw1, mw1T, 1024, 512);
    tconv_k<<<dim3(32, 128), 256, 0, stream>>>(fw1, fw1T, 1024, 4096);
    tconv_k<<<dim3(128, 32), 256, 0, stream>>>(fw2, fw2T, 4096, 1024);

    // --- position/timing: pp = pe@wiT + bi (small GEMM), then full-chip add ---
    build_pe_k<<<4096, 256, 0, stream>>>(pos_table, time_tab, pe);
    gemm_ring<0><<<64, 256, 0, stream>>>(pe, wiT, bi, nullptr,
                                         pp, nullptr, nullptr, 1024, 1024, 1024);
    add_pe_k<<<8192, 256, 0, stream>>>((const float4*)x, (const float4*)pp, (float4*)xacc);

    // --- attention block ---
    layernorm_k<<<NROWS, 256, 0, stream>>>(xacc, g1, be1, h_bf);
    gemm_ring<3><<<1280, 256, 0, stream>>>(h_bf, qwT, catb, nullptr,
                                           q_bf, k_bf, tmh, NROWS, 2560, 1024);
    gemm_ring<4><<<512, 256, 0, stream>>>(vwT, h_bf, vb, nullptr,
                                          vTb, nullptr, nullptr, 1024, 8192, 1024);
    mech_head_k<<<2048, 256, 0, stream>>>(tmh, mw2, mb2, mech);

    attn_mfma_k<<<1024, 512, 0, stream>>>(q_bf, k_bf, vTb, mech, ctxb);
    gemm_ring<0><<<512, 256, 0, stream>>>(ctxb, owT, ob, xacc,
                                          xacc, nullptr, nullptr, NROWS, 1024, 1024);

    // --- five elements ---
    layernorm_k<<<NROWS, 256, 0, stream>>>(xacc, g2, be2, h_bf);
    gemm_ring<0><<<512, 256, 0, stream>>>(h_bf, w5T, b5, xacc,
                                          xacc, nullptr, nullptr, NROWS, 1024, 1024);

    // --- FFN ---
    layernorm_k<<<NROWS, 256, 0, stream>>>(xacc, g3, be3, h_bf);
    gemm_ring<2><<<2048, 256, 0, stream>>>(h_bf, fw1T, fb1, nullptr,
                                           ffn1, nullptr, nullptr, NROWS, DFFN, 1024);
    gemm_ring<0><<<512, 256, 0, stream>>>(ffn1, fw2T, fb2, xacc,
                                          out, nullptr, nullptr, NROWS, 1024, DFFN);
}